// Round 2
// baseline (175.432 us; speedup 1.0000x reference)
//
#include <hip/hip_runtime.h>
#include <math.h>

#define B_ 32
#define NODES_ 512
#define IN_ 256
#define OUT_ 128
#define CAPS_ 16
#define KW_ 5
#define M_ (B_*NODES_)            // 16384
#define NCH 32                    // node chunks of 16

// ---- workspace layout (floats) ----
#define Y_OFF 0
#define Y_SZ  (M_*KW_*OUT_)       // 10,485,760  (41.9 MB)
#define L_OFF (Y_OFF + Y_SZ)
#define L_SZ  (B_*CAPS_*NODES_)   // 262,144
#define V_OFF (L_OFF + L_SZ)
#define V_SZ  (B_*CAPS_*OUT_)     // 65,536
#define SP_OFF (V_OFF + V_SZ)
#define SP_SZ (B_*NCH*CAPS_*OUT_) // 2,097,152
// total ~12.9M floats ~52 MB

// ============================================================
// Kernel 1: y[(b,n), k, o] = sum_i x[(b,n), i] * W[k, i, o]
// One GEMM [16384 x 256] @ [256 x 128] per k (blockIdx.y).
// BM=64, BN=128(full), BK=32. 256 threads, 4x8 outputs/thread.
// ============================================================
__global__ __launch_bounds__(256) void gemm_y(const float* __restrict__ x,
                                              const float* __restrict__ W,
                                              float* __restrict__ y) {
  __shared__ __align__(16) float Ast[32*68];   // [kk][row], pad 68
  __shared__ __align__(16) float Bs[32*132];   // [kk][o],  pad 132
  const int t  = threadIdx.x;
  const int mb = blockIdx.x;      // 0..255
  const int k  = blockIdx.y;      // 0..4
  const int tx = t & 15;          // col group: cols {tx*4+j} and {64+tx*4+j}
  const int ty = t >> 4;          // row group 0..15: rows ty*4+i

  const float* Wk = W + (size_t)k*IN_*OUT_;
  const float* xb = x + (size_t)mb*64*IN_;

  float acc[4][8];
  #pragma unroll
  for (int i=0;i<4;++i)
    #pragma unroll
    for (int j=0;j<8;++j) acc[i][j]=0.f;

  for (int kb=0; kb<IN_; kb+=32) {
    // A: 64 rows x 32 cols -> store transposed Ast[kk][row]
    {
      int r  = t >> 3;      // 0..31
      int c4 = t & 7;       // 0..7
      #pragma unroll
      for (int h=0; h<2; ++h) {
        int rr = r + h*32;
        float4 a = *(const float4*)(xb + (size_t)rr*IN_ + kb + c4*4);
        Ast[(c4*4+0)*68 + rr] = a.x;
        Ast[(c4*4+1)*68 + rr] = a.y;
        Ast[(c4*4+2)*68 + rr] = a.z;
        Ast[(c4*4+3)*68 + rr] = a.w;
      }
    }
    // B: 32 rows x 128 cols
    {
      int kk0 = t >> 5;     // 0..7
      int c4  = t & 31;     // 0..31
      #pragma unroll
      for (int q=0; q<4; ++q) {
        int row = kk0 + q*8;
        float4 bv = *(const float4*)(Wk + (size_t)(kb+row)*OUT_ + c4*4);
        *(float4*)&Bs[row*132 + c4*4] = bv;
      }
    }
    __syncthreads();
    #pragma unroll
    for (int kk=0; kk<32; ++kk) {
      float4 a4 = *(const float4*)&Ast[kk*68 + ty*4];
      float4 b0 = *(const float4*)&Bs[kk*132 + tx*4];
      float4 b1 = *(const float4*)&Bs[kk*132 + 64 + tx*4];
      float av[4] = {a4.x,a4.y,a4.z,a4.w};
      float bv[8] = {b0.x,b0.y,b0.z,b0.w,b1.x,b1.y,b1.z,b1.w};
      #pragma unroll
      for (int i=0;i<4;++i)
        #pragma unroll
        for (int j=0;j<8;++j)
          acc[i][j] += av[i]*bv[j];
    }
    __syncthreads();
  }
  // write out: cols tx*4..+3 and 64+tx*4..+3
  #pragma unroll
  for (int i=0;i<4;++i) {
    int row = mb*64 + ty*4 + i;
    float* dst = y + ((size_t)row*KW_ + k)*OUT_;
    float4 o0 = {acc[i][0],acc[i][1],acc[i][2],acc[i][3]};
    float4 o1 = {acc[i][4],acc[i][5],acc[i][6],acc[i][7]};
    *(float4*)(dst + tx*4)      = o0;
    *(float4*)(dst + 64 + tx*4) = o1;
  }
}

// ============================================================
// Kernel 2: one routing sweep for 16 nodes of one batch b.
// mode 0: init logits from contribution, c = 1/16 uniform.
// mode 1: a = u.v ; logits += a ; c = softmax(logits).
// Always: accumulate partial s[c][o] over the 16 nodes -> s_part.
// u[c][o] recomputed on the fly from y (5 FMA) - never stored.
// ============================================================
__global__ __launch_bounds__(256) void route_step(const float* __restrict__ y,
                                                  const float* __restrict__ alpha,
                                                  const float* __restrict__ contrib,
                                                  float* __restrict__ logits,
                                                  const float* __restrict__ vin,
                                                  float* __restrict__ s_part,
                                                  int mode) {
  __shared__ __align__(16) float sh_y[16*644];      // [node][k*128+o], pad 644
  __shared__ __align__(16) float sh_v[16*132];      // [cap][o], pad 132
  __shared__ __align__(16) float sh_alpha[16*16*5]; // [node][cap][k]
  __shared__ float sh_logit[16][16];                // [node][cap]
  __shared__ float sh_cw[16][16];                   // [node][cap]

  const int t  = threadIdx.x;
  const int ch = blockIdx.x;   // 0..31
  const int b  = blockIdx.y;   // 0..31
  const int n0 = ch*16;

  // ---- stage y: 16 nodes x 640 contiguous floats ----
  const float* ybase = y + ((size_t)(b*NODES_ + n0))*KW_*OUT_;
  #pragma unroll
  for (int q=0; q<10; ++q) {
    int idx4 = t + q*256;           // 0..2559
    int flat = idx4*4;
    int node = flat / 640;
    int rem  = flat - node*640;
    float4 vv = *(const float4*)(ybase + flat);
    *(float4*)&sh_y[node*644 + rem] = vv;
  }
  // ---- stage alpha: 16 nodes x 80 floats = 320 float4 (strided: 256 thr) ----
  const float* abase = alpha + (size_t)n0*CAPS_*KW_;
  for (int i = t; i < 320; i += 256) {
    float4 av = *(const float4*)(abase + i*4);
    *(float4*)&sh_alpha[i*4] = av;
  }
  if (mode >= 1) {
    // stage v[b]: 16 caps x 128
    const float* vbase = vin + (size_t)b*CAPS_*OUT_;
    #pragma unroll
    for (int q=0; q<2; ++q) {
      int idx4 = t + q*256;
      int flat = idx4*4;
      int c = flat >> 7;
      int o = flat & 127;
      float4 vv = *(const float4*)(vbase + flat);
      *(float4*)&sh_v[c*132 + o] = vv;
    }
    int node = t & 15, cap = t >> 4;
    sh_logit[node][cap] = logits[((size_t)b*CAPS_ + cap)*NODES_ + n0 + node];
  } else {
    int node = t & 15, cap = t >> 4;
    float cv = contrib[(size_t)b*NODES_ + n0 + node];
    sh_logit[node][cap] = cv;
    logits[((size_t)b*CAPS_ + cap)*NODES_ + n0 + node] = cv;
  }
  __syncthreads();

  if (mode >= 1) {
    // ---- phase 1: a[node][cap] = sum_o u*v, one thread per (node,cap) ----
    int node = t >> 4, cap = t & 15;
    const float* al = &sh_alpha[(node*16+cap)*5];
    float a0=al[0],a1=al[1],a2=al[2],a3=al[3],a4=al[4];
    const float* yb = &sh_y[node*644];
    const float* vb = &sh_v[cap*132];
    float accd = 0.f;
    #pragma unroll 4
    for (int o=0; o<128; o+=4) {
      float4 y0 = *(const float4*)(yb + 0*128 + o);
      float4 y1 = *(const float4*)(yb + 1*128 + o);
      float4 y2 = *(const float4*)(yb + 2*128 + o);
      float4 y3 = *(const float4*)(yb + 3*128 + o);
      float4 y4 = *(const float4*)(yb + 4*128 + o);
      float4 vv = *(const float4*)(vb + o);
      float ux = a0*y0.x + a1*y1.x + a2*y2.x + a3*y3.x + a4*y4.x;
      float uy = a0*y0.y + a1*y1.y + a2*y2.y + a3*y3.y + a4*y4.y;
      float uz = a0*y0.z + a1*y1.z + a2*y2.z + a3*y3.z + a4*y4.z;
      float uw = a0*y0.w + a1*y1.w + a2*y2.w + a3*y3.w + a4*y4.w;
      accd += ux*vv.x + uy*vv.y + uz*vv.z + uw*vv.w;
    }
    float newl = sh_logit[node][cap] + accd;
    sh_logit[node][cap] = newl;
    logits[((size_t)b*CAPS_ + cap)*NODES_ + n0 + node] = newl;
    __syncthreads();
    // softmax over caps, one thread per node
    if (t < 16) {
      int nd = t;
      float m = -1e30f;
      #pragma unroll
      for (int c=0;c<16;++c) m = fmaxf(m, sh_logit[nd][c]);
      float s = 0.f;
      float e[16];
      #pragma unroll
      for (int c=0;c<16;++c) { e[c] = __expf(sh_logit[nd][c]-m); s += e[c]; }
      float inv = 1.f/s;
      #pragma unroll
      for (int c=0;c<16;++c) sh_cw[nd][c] = e[c]*inv;
    }
  } else {
    int node = t >> 4, cap = t & 15;
    sh_cw[node][cap] = 1.f/16.f;
  }
  __syncthreads();

  // ---- phase 2: s_part[c][o] = sum_node cw * u ----
  float* spb = s_part + ((size_t)(b*NCH + ch))*CAPS_*OUT_;
  #pragma unroll
  for (int sl=0; sl<2; ++sl) {
    int slot = t + sl*256;
    int c = slot >> 5;          // 0..15
    int o = (slot & 31) * 4;    // 0..124
    float4 acc = {0.f,0.f,0.f,0.f};
    #pragma unroll 4
    for (int nd=0; nd<16; ++nd) {
      const float* al = &sh_alpha[(nd*16+c)*5];
      float a0=al[0],a1=al[1],a2=al[2],a3=al[3],a4=al[4];
      const float* yb = &sh_y[nd*644 + o];
      float4 y0 = *(const float4*)(yb);
      float4 y1 = *(const float4*)(yb + 128);
      float4 y2 = *(const float4*)(yb + 256);
      float4 y3 = *(const float4*)(yb + 384);
      float4 y4 = *(const float4*)(yb + 512);
      float cw = sh_cw[nd][c];
      acc.x += cw*(a0*y0.x + a1*y1.x + a2*y2.x + a3*y3.x + a4*y4.x);
      acc.y += cw*(a0*y0.y + a1*y1.y + a2*y2.y + a3*y3.y + a4*y4.y);
      acc.z += cw*(a0*y0.z + a1*y1.z + a2*y2.z + a3*y3.z + a4*y4.z);
      acc.w += cw*(a0*y0.w + a1*y1.w + a2*y2.w + a3*y3.w + a4*y4.w);
    }
    *(float4*)(spb + c*OUT_ + o) = acc;
  }
}

// ============================================================
// Kernel 3: reduce s_part over chunks, squash, write v (or d_out).
// One block per (b,c), 128 threads (one per o).
// ============================================================
__global__ __launch_bounds__(128) void squash_k(const float* __restrict__ s_part,
                                                float* __restrict__ out) {
  const int bc = blockIdx.x;       // b*16+c
  const int o  = threadIdx.x;      // 0..127
  const int b = bc >> 4, c = bc & 15;
  const float* sp = s_part + ((size_t)(b*NCH)*CAPS_ + c)*OUT_ + o;
  float s = 0.f;
  #pragma unroll
  for (int ch=0; ch<NCH; ++ch) s += sp[(size_t)ch*CAPS_*OUT_];
  float ss = s*s;
  #pragma unroll
  for (int off=32; off>0; off>>=1) ss += __shfl_down(ss, off, 64);
  __shared__ float red[2];
  if ((o & 63) == 0) red[o>>6] = ss;
  __syncthreads();
  float sn = red[0] + red[1];
  float scale = (sn/(1.f+sn)) / (sqrtf(sn)+1e-8f);
  out[(size_t)bc*OUT_ + o] = scale*s;
}

// ============================================================
extern "C" void kernel_launch(void* const* d_in, const int* in_sizes, int n_in,
                              void* d_out, int out_size, void* d_ws, size_t ws_size,
                              hipStream_t stream) {
  const float* x       = (const float*)d_in[0];
  const float* contrib = (const float*)d_in[1];
  const float* W       = (const float*)d_in[2];
  const float* alpha   = (const float*)d_in[3];
  float* out = (float*)d_out;
  float* ws  = (float*)d_ws;

  float* y      = ws + Y_OFF;
  float* logits = ws + L_OFF;
  float* v      = ws + V_OFF;
  float* s_part = ws + SP_OFF;

  // y = x @ W_k  for each k
  gemm_y<<<dim3(M_/64, KW_), 256, 0, stream>>>(x, W, y);

  // iter 0: uniform c (softmax of constant logits), init logits
  route_step<<<dim3(NCH, B_), 256, 0, stream>>>(y, alpha, contrib, logits, v, s_part, 0);
  squash_k<<<B_*CAPS_, 128, 0, stream>>>(s_part, v);

  // 3 routing updates; last squash writes final output
  for (int it=0; it<3; ++it) {
    route_step<<<dim3(NCH, B_), 256, 0, stream>>>(y, alpha, contrib, logits, v, s_part, 1);
    squash_k<<<B_*CAPS_, 128, 0, stream>>>(s_part, (it==2) ? out : v);
  }
}

// Round 5
// 153.439 us; speedup vs baseline: 1.1433x; 1.1433x over previous
//
#include <hip/hip_runtime.h>
#include <math.h>

#define B_ 32
#define NODES_ 512
#define IN_ 256
#define OUT_ 128
#define CAPS_ 16
#define KW_ 5
#define M_ (B_*NODES_)            // 16384
#define N_ (KW_*OUT_)             // 640
#define NCH 32                    // node chunks of 16

typedef __attribute__((ext_vector_type(8))) short short8;
typedef __attribute__((ext_vector_type(4))) float f32x4;

// ---- workspace layout (bytes) ----  total 51,642,368 (== round-1 proven size)
// y f32 [16384][640]             : 41,943,040
// logits f32 [B][CAPS][NODES]    :  1,048,576
// v f32 [B][CAPS][OUT]           :    262,144
// s_part f32 [B][NCH][CAPS][OUT] :  8,388,608
// bThi/bTlo bf16 [640][256]      : aliased inside s_part (used only pre-routing)
#define Y_BOFF   0
#define L_BOFF   41943040
#define V_BOFF   42991616
#define SP_BOFF  43253760
#define BT_SZ    (N_*IN_*2)       // 327,680 bytes each

__device__ __forceinline__ float b2f(unsigned short u) {
  union { unsigned int i; float f; } c; c.i = ((unsigned int)u) << 16; return c.f;
}

// f32 -> bf16 with round-to-nearest-even (finite inputs only)
__device__ __forceinline__ unsigned short f2b(float f) {
  union { float f; unsigned int i; } c; c.f = f;
  unsigned int u = c.i;
  u += 0x7fffu + ((u >> 16) & 1u);
  return (unsigned short)(u >> 16);
}

__device__ __forceinline__ void async_load16(const void* g, void* l) {
  __builtin_amdgcn_global_load_lds(
      (const __attribute__((address_space(1))) unsigned int*)g,
      (__attribute__((address_space(3))) unsigned int*)l, 16, 0, 0);
}

// ============================================================
// conv_w: split W into bThi/bTlo: bT*[n=k*128+o][i] = W[k][i][o]
// ============================================================
__global__ __launch_bounds__(256) void conv_w(const float* __restrict__ W,
                                              unsigned short* __restrict__ bThi,
                                              unsigned short* __restrict__ bTlo) {
  int n = blockIdx.x;           // 0..639
  int i = threadIdx.x;          // 0..255
  int k = n >> 7, o = n & 127;
  float v = W[((size_t)k*IN_ + i)*OUT_ + o];
  unsigned short h = f2b(v);
  bThi[(size_t)n*IN_ + i] = h;
  bTlo[(size_t)n*IN_ + i] = f2b(v - b2f(h));
}

// ============================================================
// gemm_mfma: y[m][n] = sum_i x[m][i] * bT[n][i]  (f32 in/out,
// split-bf16 MFMA: hi*hi + hi*lo + lo*hi, f32 accumulate)
// 128x128 tile, BK=32, 4 waves (2x2), 4x4 frags of mfma 16x16x32.
// A staged as f32 (chunk layout [cg=4floats][row]); B hi/lo bf16
// chunk layout [cg=8elems][row]. Swapped-operand mfma -> n-quad in
// regs -> float4 y stores.
// ============================================================
__global__ __launch_bounds__(256) void gemm_mfma(const float* __restrict__ x,
                                                 const unsigned short* __restrict__ bThi,
                                                 const unsigned short* __restrict__ bTlo,
                                                 float* __restrict__ y) {
  __shared__ float A_lds[8*128*4];    // 16 KB
  __shared__ short Bh_lds[4*128*8];   // 8 KB
  __shared__ short Bl_lds[4*128*8];   // 8 KB
  const int t    = threadIdx.x;
  const int w    = t >> 6;          // wave 0..3
  const int lane = t & 63;
  const int wm   = w >> 1;          // 0..1
  const int wn   = w & 1;           // 0..1
  const int m0   = blockIdx.x * 128;
  const int n0   = blockIdx.y * 128;
  const int lrow = lane & 15;
  const int lk   = lane >> 4;       // 0..3

  f32x4 acc[4][4];
  #pragma unroll
  for (int i=0;i<4;++i)
    #pragma unroll
    for (int j=0;j<4;++j) acc[i][j] = (f32x4){0.f,0.f,0.f,0.f};

  for (int kb = 0; kb < IN_; kb += 32) {
    // ---- stage A (f32, 1024 chunks) ----
    #pragma unroll
    for (int q=0; q<4; ++q) {
      int d0 = q*256 + w*64;
      int d  = d0 + lane;
      int cg = d >> 7;           // 0..7 (4-float group)
      int r  = d & 127;
      async_load16(x + (size_t)(m0 + r)*IN_ + kb + cg*4, &A_lds[d0*4]);
    }
    // ---- stage B hi/lo (bf16, 512 chunks each) ----
    #pragma unroll
    for (int q=0; q<2; ++q) {
      int d0 = q*256 + w*64;
      int d  = d0 + lane;
      int cg = d >> 7;           // 0..3 (8-elem group)
      int r  = d & 127;
      async_load16(bThi + (size_t)(n0 + r)*IN_ + kb + cg*8, &Bh_lds[d0*8]);
      async_load16(bTlo + (size_t)(n0 + r)*IN_ + kb + cg*8, &Bl_lds[d0*8]);
    }
    __syncthreads();

    short8 ah[4], al[4], bh[4], bl[4];
    #pragma unroll
    for (int mi=0; mi<4; ++mi) {
      int row_a = wm*64 + mi*16 + lrow;
      f32x4 a0 = *(const f32x4*)&A_lds[((2*lk  )*128 + row_a)*4];
      f32x4 a1 = *(const f32x4*)&A_lds[((2*lk+1)*128 + row_a)*4];
      #pragma unroll
      for (int j=0; j<8; ++j) {
        float f = (j < 4) ? a0[j] : a1[j-4];
        unsigned short h = f2b(f);
        ah[mi][j] = (short)h;
        al[mi][j] = (short)f2b(f - b2f(h));
      }
    }
    #pragma unroll
    for (int ni=0; ni<4; ++ni) {
      int row_b = wn*64 + ni*16 + lrow;
      bh[ni] = *(const short8*)&Bh_lds[(lk*128 + row_b)*8];
      bl[ni] = *(const short8*)&Bl_lds[(lk*128 + row_b)*8];
    }
    #pragma unroll
    for (int mi=0; mi<4; ++mi)
      #pragma unroll
      for (int ni=0; ni<4; ++ni) {
        acc[mi][ni] = __builtin_amdgcn_mfma_f32_16x16x32_bf16(bh[ni], ah[mi], acc[mi][ni], 0, 0, 0);
        acc[mi][ni] = __builtin_amdgcn_mfma_f32_16x16x32_bf16(bh[ni], al[mi], acc[mi][ni], 0, 0, 0);
        acc[mi][ni] = __builtin_amdgcn_mfma_f32_16x16x32_bf16(bl[ni], ah[mi], acc[mi][ni], 0, 0, 0);
      }
    __syncthreads();
  }

  // epilogue: lane holds C[m = col = lane&15][n = row-quad = (lane>>4)*4+reg]
  #pragma unroll
  for (int mi=0; mi<4; ++mi) {
    int m = m0 + wm*64 + mi*16 + lrow;
    #pragma unroll
    for (int ni=0; ni<4; ++ni) {
      int nb = n0 + wn*64 + ni*16 + lk*4;
      float4 o = {acc[mi][ni][0], acc[mi][ni][1], acc[mi][ni][2], acc[mi][ni][3]};
      *(float4*)(y + (size_t)m*N_ + nb) = o;
    }
  }
}

// ============================================================
// route_step: one routing sweep for 16 nodes of one batch b. (f32 y)
// mode 0: init logits from contribution, c = 1/16 uniform.
// mode 1: a = u.v ; logits += a ; c = softmax(logits).
// u[c][o] recomputed on the fly from y (5 FMA) - never stored.
// ============================================================
__global__ __launch_bounds__(256) void route_step(const float* __restrict__ y,
                                                  const float* __restrict__ alpha,
                                                  const float* __restrict__ contrib,
                                                  float* __restrict__ logits,
                                                  const float* __restrict__ vin,
                                                  float* __restrict__ s_part,
                                                  int mode) {
  __shared__ __align__(16) float sh_y[16*644];      // [node][k*128+o], pad 644
  __shared__ __align__(16) float sh_v[16*132];      // [cap][o], pad 132
  __shared__ __align__(16) float sh_alpha[16*16*5]; // [node][cap][k]
  __shared__ float sh_logit[16][16];                // [node][cap]
  __shared__ float sh_cw[16][16];                   // [node][cap]

  const int t  = threadIdx.x;
  const int ch = blockIdx.x;   // 0..31
  const int b  = blockIdx.y;   // 0..31
  const int n0 = ch*16;

  // ---- stage y: 16 nodes x 640 contiguous floats ----
  const float* ybase = y + ((size_t)(b*NODES_ + n0))*KW_*OUT_;
  #pragma unroll
  for (int q=0; q<10; ++q) {
    int idx4 = t + q*256;           // 0..2559
    int flat = idx4*4;
    int node = flat / 640;
    int rem  = flat - node*640;
    float4 vv = *(const float4*)(ybase + flat);
    *(float4*)&sh_y[node*644 + rem] = vv;
  }
  // ---- stage alpha: 320 float4 strided over 256 threads ----
  const float* abase = alpha + (size_t)n0*CAPS_*KW_;
  for (int i = t; i < 320; i += 256) {
    float4 av = *(const float4*)(abase + i*4);
    *(float4*)&sh_alpha[i*4] = av;
  }
  if (mode >= 1) {
    const float* vbase = vin + (size_t)b*CAPS_*OUT_;
    #pragma unroll
    for (int q=0; q<2; ++q) {
      int flat = (t + q*256)*4;
      int c = flat >> 7, o = flat & 127;
      float4 vv = *(const float4*)(vbase + flat);
      *(float4*)&sh_v[c*132 + o] = vv;
    }
    int node = t & 15, cap = t >> 4;
    sh_logit[node][cap] = logits[((size_t)b*CAPS_ + cap)*NODES_ + n0 + node];
  } else {
    int node = t & 15, cap = t >> 4;
    float cv = contrib[(size_t)b*NODES_ + n0 + node];
    sh_logit[node][cap] = cv;
    logits[((size_t)b*CAPS_ + cap)*NODES_ + n0 + node] = cv;
  }
  __syncthreads();

  if (mode >= 1) {
    // ---- phase 1: a[node][cap] = sum_o u*v, one thread per (node,cap) ----
    int node = t >> 4, cap = t & 15;
    const float* al = &sh_alpha[(node*16+cap)*5];
    float a0=al[0],a1=al[1],a2=al[2],a3=al[3],a4=al[4];
    const float* yb = &sh_y[node*644];
    const float* vb = &sh_v[cap*132];
    float accd = 0.f;
    #pragma unroll 4
    for (int o=0; o<128; o+=4) {
      float4 y0 = *(const float4*)(yb + 0*128 + o);
      float4 y1 = *(const float4*)(yb + 1*128 + o);
      float4 y2 = *(const float4*)(yb + 2*128 + o);
      float4 y3 = *(const float4*)(yb + 3*128 + o);
      float4 y4 = *(const float4*)(yb + 4*128 + o);
      float4 vv = *(const float4*)(vb + o);
      float ux = a0*y0.x + a1*y1.x + a2*y2.x + a3*y3.x + a4*y4.x;
      float uy = a0*y0.y + a1*y1.y + a2*y2.y + a3*y3.y + a4*y4.y;
      float uz = a0*y0.z + a1*y1.z + a2*y2.z + a3*y3.z + a4*y4.z;
      float uw = a0*y0.w + a1*y1.w + a2*y2.w + a3*y3.w + a4*y4.w;
      accd += ux*vv.x + uy*vv.y + uz*vv.z + uw*vv.w;
    }
    float newl = sh_logit[node][cap] + accd;
    sh_logit[node][cap] = newl;
    logits[((size_t)b*CAPS_ + cap)*NODES_ + n0 + node] = newl;
    __syncthreads();
    // softmax over caps, one thread per node
    if (t < 16) {
      int nd = t;
      float m = -1e30f;
      #pragma unroll
      for (int c=0;c<16;++c) m = fmaxf(m, sh_logit[nd][c]);
      float s = 0.f;
      float e[16];
      #pragma unroll
      for (int c=0;c<16;++c) { e[c] = __expf(sh_logit[nd][c]-m); s += e[c]; }
      float inv = 1.f/s;
      #pragma unroll
      for (int c=0;c<16;++c) sh_cw[nd][c] = e[c]*inv;
    }
  } else {
    int node = t >> 4, cap = t & 15;
    sh_cw[node][cap] = 1.f/16.f;
  }
  __syncthreads();

  // ---- phase 2: s_part[c][o] = sum_node cw * u ----
  float* spb = s_part + ((size_t)(b*NCH + ch))*CAPS_*OUT_;
  #pragma unroll
  for (int sl=0; sl<2; ++sl) {
    int slot = t + sl*256;
    int c = slot >> 5;          // 0..15
    int o = (slot & 31) * 4;    // 0..124
    float4 acc = {0.f,0.f,0.f,0.f};
    #pragma unroll 4
    for (int nd=0; nd<16; ++nd) {
      const float* al = &sh_alpha[(nd*16+c)*5];
      float a0=al[0],a1=al[1],a2=al[2],a3=al[3],a4=al[4];
      const float* yb = &sh_y[nd*644 + o];
      float4 y0 = *(const float4*)(yb);
      float4 y1 = *(const float4*)(yb + 128);
      float4 y2 = *(const float4*)(yb + 256);
      float4 y3 = *(const float4*)(yb + 384);
      float4 y4 = *(const float4*)(yb + 512);
      float cw = sh_cw[nd][c];
      acc.x += cw*(a0*y0.x + a1*y1.x + a2*y2.x + a3*y3.x + a4*y4.x);
      acc.y += cw*(a0*y0.y + a1*y1.y + a2*y2.y + a3*y3.y + a4*y4.y);
      acc.z += cw*(a0*y0.z + a1*y1.z + a2*y2.z + a3*y3.z + a4*y4.z);
      acc.w += cw*(a0*y0.w + a1*y1.w + a2*y2.w + a3*y3.w + a4*y4.w);
    }
    *(float4*)(spb + c*OUT_ + o) = acc;
  }
}

// ============================================================
// squash_k: reduce s_part over chunks, squash, write v (or out)
// ============================================================
__global__ __launch_bounds__(128) void squash_k(const float* __restrict__ s_part,
                                                float* __restrict__ out) {
  const int bc = blockIdx.x;       // b*16+c
  const int o  = threadIdx.x;      // 0..127
  const int b = bc >> 4, c = bc & 15;
  const float* sp = s_part + ((size_t)(b*NCH)*CAPS_ + c)*OUT_ + o;
  float s = 0.f;
  #pragma unroll
  for (int ch=0; ch<NCH; ++ch) s += sp[(size_t)ch*CAPS_*OUT_];
  float ss = s*s;
  #pragma unroll
  for (int off=32; off>0; off>>=1) ss += __shfl_down(ss, off, 64);
  __shared__ float red[2];
  if ((o & 63) == 0) red[o>>6] = ss;
  __syncthreads();
  float sn = red[0] + red[1];
  float scale = (sn/(1.f+sn)) / (sqrtf(sn)+1e-8f);
  out[(size_t)bc*OUT_ + o] = scale*s;
}

// ============================================================
extern "C" void kernel_launch(void* const* d_in, const int* in_sizes, int n_in,
                              void* d_out, int out_size, void* d_ws, size_t ws_size,
                              hipStream_t stream) {
  const float* x       = (const float*)d_in[0];
  const float* contrib = (const float*)d_in[1];
  const float* W       = (const float*)d_in[2];
  const float* alpha   = (const float*)d_in[3];
  float* out = (float*)d_out;
  char*  wsb = (char*)d_ws;

  float* y             = (float*)(wsb + Y_BOFF);
  float* logits        = (float*)(wsb + L_BOFF);
  float* v             = (float*)(wsb + V_BOFF);
  float* s_part        = (float*)(wsb + SP_BOFF);
  // bT hi/lo alias the s_part region (consumed before s_part is first written)
  unsigned short* bThi = (unsigned short*)(wsb + SP_BOFF);
  unsigned short* bTlo = (unsigned short*)(wsb + SP_BOFF + BT_SZ);

  conv_w<<<N_, 256, 0, stream>>>(W, bThi, bTlo);
  gemm_mfma<<<dim3(M_/128, N_/128), 256, 0, stream>>>(x, bThi, bTlo, y);

  route_step<<<dim3(NCH, B_), 256, 0, stream>>>(y, alpha, contrib, logits, v, s_part, 0);
  squash_k<<<B_*CAPS_, 128, 0, stream>>>(s_part, v);

  for (int it=0; it<3; ++it) {
    route_step<<<dim3(NCH, B_), 256, 0, stream>>>(y, alpha, contrib, logits, v, s_part, 1);
    squash_k<<<B_*CAPS_, 128, 0, stream>>>(s_part, (it==2) ? out : v);
  }
}